// Round 10
// baseline (394.181 us; speedup 1.0000x reference)
//
#include <hip/hip_runtime.h>

typedef unsigned short u16;
typedef u16   u16x8  __attribute__((ext_vector_type(8)));
typedef u16   u16x4  __attribute__((ext_vector_type(4)));
typedef u16   u16x2  __attribute__((ext_vector_type(2)));
typedef short short8v __attribute__((ext_vector_type(8)));
typedef float f32x16  __attribute__((ext_vector_type(16)));
typedef float f32x4   __attribute__((ext_vector_type(4)));

__device__ __forceinline__ u16 f2bf(float f) {
    unsigned u = __float_as_uint(f);
    unsigned r = (u + 0x7fffu + ((u >> 16) & 1u)) >> 16;   // round-to-nearest-even
    return (u16)r;
}
__device__ __forceinline__ float bf2f(u16 h) {
    return __uint_as_float(((unsigned)h) << 16);
}

// ---------------------------------------------------------------------------
// histA (+ wconv folded into grid tail): per-bucket edge counts.
// Buckets of 512 nodes (dst>>9).
// ---------------------------------------------------------------------------
__global__ __launch_bounds__(256) void histA_wconv(const int* __restrict__ ei, int E,
                                                   int* __restrict__ bhist, int ebk,
                                                   const float* __restrict__ W1,
                                                   const float* __restrict__ W2,
                                                   const float* __restrict__ W3,
                                                   u16* __restrict__ WT1,
                                                   u16* __restrict__ WT2,
                                                   u16* __restrict__ WT3) {
    if ((int)blockIdx.x >= ebk) {
        // weight convert: W[k][col] fp32 -> WT[col][k] bf16 (W3 padded to 64 cols)
        int i = (blockIdx.x - ebk) * 256 + threadIdx.x;   // 0..40959
        if (i < 32768) {
            const float* W = (i < 16384) ? W1 : W2;
            u16* WT = (i < 16384) ? WT1 : WT2;
            int j = i & 16383;
            int k = j >> 7, col = j & 127;
            WT[col * 128 + k] = f2bf(W[j]);
        } else {
            int j = i - 32768;                    // 0..8191
            int col = j >> 7, k = j & 127;        // col 0..63
            WT3[j] = (col < 40) ? f2bf(W3[k * 40 + col]) : (u16)0;
        }
        return;
    }
    __shared__ int h[512];
    int t = threadIdx.x;
    h[t] = 0; h[t + 256] = 0;
    __syncthreads();
    int base = blockIdx.x * 4096 + t;
#pragma unroll
    for (int j = 0; j < 16; j++) {
        int e = base + j * 256;
        if (e < E) {
            int d = __builtin_nontemporal_load(ei + E + e);
            atomicAdd(&h[d >> 9], 1);
        }
    }
    __syncthreads();
    if (h[t])       atomicAdd(&bhist[t], h[t]);
    if (h[t + 256]) atomicAdd(&bhist[t + 256], h[t + 256]);
}

__global__ __launch_bounds__(256) void scanA_kernel(const int* __restrict__ bhist,
                                                    int* __restrict__ bstart,
                                                    int* __restrict__ bcur, int nb) {
    __shared__ int hh[512];
    __shared__ int ps[256];
    int t = threadIdx.x;
    hh[t]       = (t < nb) ? bhist[t] : 0;
    hh[t + 256] = (t + 256 < nb) ? bhist[t + 256] : 0;
    __syncthreads();
    int a0 = hh[2 * t], a1 = hh[2 * t + 1];
    int s = a0 + a1;
    ps[t] = s;
    __syncthreads();
    for (int off = 1; off < 256; off <<= 1) {
        int add = (t >= off) ? ps[t - off] : 0;
        __syncthreads();
        ps[t] += add;
        __syncthreads();
    }
    int ex = ps[t] - s;
    bstart[2 * t] = ex;         bcur[2 * t] = ex;
    bstart[2 * t + 1] = ex + a0; bcur[2 * t + 1] = ex + a0;
    if (t == 255) bstart[512] = ps[255];
}

__global__ __launch_bounds__(256) void bucket_scatter(const int* __restrict__ ei, int E,
                                                      int* __restrict__ bcur,
                                                      int2* __restrict__ ebuf) {
    __shared__ int h[512];
    __shared__ int gb[512];
    int t = threadIdx.x;
    h[t] = 0; h[t + 256] = 0;
    __syncthreads();
    int base = blockIdx.x * 4096 + t;
    int ss[16], dd[16], lr[16];
#pragma unroll
    for (int j = 0; j < 16; j++) {
        int e = base + j * 256;
        if (e < E) {
            ss[j] = __builtin_nontemporal_load(ei + e);
            dd[j] = __builtin_nontemporal_load(ei + E + e);
            lr[j] = atomicAdd(&h[dd[j] >> 9], 1);
        } else {
            dd[j] = -1;
        }
    }
    __syncthreads();
    if (h[t])       gb[t] = atomicAdd(&bcur[t], h[t]);
    if (h[t + 256]) gb[t + 256] = atomicAdd(&bcur[t + 256], h[t + 256]);
    __syncthreads();
#pragma unroll
    for (int j = 0; j < 16; j++) {
        if (dd[j] >= 0) {
            int b = dd[j] >> 9;
            ebuf[gb[b] + lr[j]] = make_int2(ss[j], dd[j]);
        }
    }
}

__global__ __launch_bounds__(256) void fine_fill(const int2* __restrict__ ebuf,
                                                 const int* __restrict__ bstart,
                                                 int* __restrict__ row_start,
                                                 float* __restrict__ dinv,
                                                 int* __restrict__ csr_src,
                                                 int n, int nb, int E) {
    __shared__ int h[512];
    __shared__ int cur[512];
    __shared__ int ps[256];
    int b = blockIdx.x;
    int t = threadIdx.x;
    int base = b << 9;
    int range = n - base; if (range > 512) range = 512;
    int bs = bstart[b], be = bstart[b + 1];

    h[t] = 0; h[t + 256] = 0;
    __syncthreads();
    for (int i = bs + t; i < be; i += 256) {
        int2 e = ebuf[i];
        atomicAdd(&h[e.y - base], 1);
    }
    __syncthreads();
    if (t < range)       dinv[base + t] = rsqrtf((float)(h[t] + 1));
    if (t + 256 < range) dinv[base + t + 256] = rsqrtf((float)(h[t + 256] + 1));
    int a0 = h[2 * t], a1 = h[2 * t + 1];
    int s = a0 + a1;
    ps[t] = s;
    __syncthreads();
    for (int off = 1; off < 256; off <<= 1) {
        int add = (t >= off) ? ps[t - off] : 0;
        __syncthreads();
        ps[t] += add;
        __syncthreads();
    }
    int ex = ps[t] - s;
    cur[2 * t] = ex;
    cur[2 * t + 1] = ex + a0;
    if (2 * t < range)     row_start[base + 2 * t] = bs + ex;
    if (2 * t + 1 < range) row_start[base + 2 * t + 1] = bs + ex + a0;
    if (b == nb - 1 && t == 0) row_start[n] = E;
    __syncthreads();
    for (int i = bs + t; i < be; i += 256) {
        int2 e = ebuf[i];
        int lp = atomicAdd(&cur[e.y - base], 1);
        csr_src[bs + lp] = e.x;
    }
}

// ---------------------------------------------------------------------------
// out[n x 128](bf16) = A[n x 128](fp32) @ W1[128 x 128] via bf16 MFMA.
// 64-row tiles: As 16KB + Bs 32KB = 48KB LDS.
// ---------------------------------------------------------------------------
__global__ __launch_bounds__(256) void gemm128_mfma(const float* __restrict__ A,
                                                    const u16* __restrict__ WT,
                                                    u16* __restrict__ out, int n) {
    __shared__ u16 As[64 * 128];
    __shared__ u16 Bs[128 * 128];
    const int t = threadIdx.x;
    const int r0 = blockIdx.x * 64;

#pragma unroll
    for (int j = 0; j < 8; j++) {
        int f = t + j * 256;
        int col = f >> 4;
        int k0 = (f & 15) * 8;
        u16x8 v = *(const u16x8*)(WT + col * 128 + k0);
        *(u16x8*)&Bs[col * 128 + (k0 ^ ((col & 7) << 3))] = v;
    }
#pragma unroll
    for (int j = 0; j < 8; j++) {
        int f = t + j * 256;            // 2048 float4 chunks
        int row = f >> 5;
        int k0 = (f & 31) * 4;
        float4 v = make_float4(0.f, 0.f, 0.f, 0.f);
        if (r0 + row < n) v = *(const float4*)(A + (size_t)(r0 + row) * 128 + k0);
        u16x4 b;
        b[0] = f2bf(v.x); b[1] = f2bf(v.y); b[2] = f2bf(v.z); b[3] = f2bf(v.w);
        *(u16x4*)&As[row * 128 + (k0 ^ ((row & 7) << 3))] = b;
    }
    __syncthreads();

    const int w = t >> 6, lane = t & 63;
    const int wr = (w >> 1) * 32;
    const int wc = (w & 1) * 64;
    const int lr = lane & 31;
    const int kj = (lane >> 5) * 8;
    const int swz = (lr & 7) << 3;

    f32x16 acc0, acc1;
#pragma unroll
    for (int i = 0; i < 16; i++) { acc0[i] = 0.f; acc1[i] = 0.f; }

#pragma unroll
    for (int ks = 0; ks < 8; ks++) {
        int ko = (ks * 16 + kj) ^ swz;
        short8v a  = *(const short8v*)&As[(wr + lr) * 128 + ko];
        short8v b0 = *(const short8v*)&Bs[(wc + lr) * 128 + ko];
        short8v b1 = *(const short8v*)&Bs[(wc + 32 + lr) * 128 + ko];
        acc0 = __builtin_amdgcn_mfma_f32_32x32x16_bf16(a, b0, acc0, 0, 0, 0);
        acc1 = __builtin_amdgcn_mfma_f32_32x32x16_bf16(a, b1, acc1, 0, 0, 0);
    }

    const int rb = (lane >> 5) * 4;
#pragma unroll
    for (int r = 0; r < 16; r++) {
        int rr = (r & 3) + 8 * (r >> 2) + rb;
        int row = r0 + wr + rr;
        if (row < n) {
            out[(size_t)row * 128 + wc + lr]      = f2bf(acc0[r]);
            out[(size_t)row * 128 + wc + 32 + lr] = f2bf(acc1[r]);
        }
    }
}

// ---------------------------------------------------------------------------
// Fused: pull-agg over 128 bf16 features (+bias+relu) -> 16 rows in LDS ->
// rows[16][128] @ WB[128 x NCT*16] via 16x16x32 MFMA, B-fragments straight
// from global (WB is L1/L2-resident). Writes product (no bias/relu) to gout.
// 16 nodes / 256-thr block, 16 lanes/node, 4/2/1 edge unroll ladder.
// ---------------------------------------------------------------------------
template <int NCT, int OSTRIDE>
__global__ __launch_bounds__(256) void agg_fuse(const u16* __restrict__ hw,
                                                const float* __restrict__ dinv,
                                                const int* __restrict__ row_start,
                                                const int* __restrict__ csr_src,
                                                const float* __restrict__ bias,
                                                const u16* __restrict__ WB,
                                                u16* __restrict__ gout, int n) {
    __shared__ u16 rows[16 * 136];
    int t = threadIdx.x;
    int node = blockIdx.x * 16 + (t >> 4);
    int f = t & 15;
    bool alive = node < n;
    u16x8 o = {0, 0, 0, 0, 0, 0, 0, 0};
    if (alive) {
        const u16x8* hw8 = (const u16x8*)hw;
        float di = dinv[node];
        float s2 = di * di;
        u16x8 v = hw8[(size_t)node * 16 + f];
        float acc[8];
#pragma unroll
        for (int j = 0; j < 8; j++) acc[j] = bf2f(v[j]) * s2;

        int e0 = row_start[node], e1 = row_start[node + 1];
        int e = e0;
        for (; e + 3 < e1; e += 4) {
            int s0v = csr_src[e], s1v = csr_src[e + 1], s2v = csr_src[e + 2], s3v = csr_src[e + 3];
            float c0 = dinv[s0v] * di, c1 = dinv[s1v] * di;
            float c2 = dinv[s2v] * di, c3 = dinv[s3v] * di;
            u16x8 u0 = hw8[(size_t)s0v * 16 + f];
            u16x8 u1 = hw8[(size_t)s1v * 16 + f];
            u16x8 u2 = hw8[(size_t)s2v * 16 + f];
            u16x8 u3 = hw8[(size_t)s3v * 16 + f];
#pragma unroll
            for (int j = 0; j < 8; j++) acc[j] = fmaf(c0, bf2f(u0[j]), acc[j]);
#pragma unroll
            for (int j = 0; j < 8; j++) acc[j] = fmaf(c1, bf2f(u1[j]), acc[j]);
#pragma unroll
            for (int j = 0; j < 8; j++) acc[j] = fmaf(c2, bf2f(u2[j]), acc[j]);
#pragma unroll
            for (int j = 0; j < 8; j++) acc[j] = fmaf(c3, bf2f(u3[j]), acc[j]);
        }
        if (e + 1 < e1) {
            int s0v = csr_src[e], s1v = csr_src[e + 1];
            float c0 = dinv[s0v] * di, c1 = dinv[s1v] * di;
            u16x8 u0 = hw8[(size_t)s0v * 16 + f];
            u16x8 u1 = hw8[(size_t)s1v * 16 + f];
#pragma unroll
            for (int j = 0; j < 8; j++) acc[j] = fmaf(c0, bf2f(u0[j]), acc[j]);
#pragma unroll
            for (int j = 0; j < 8; j++) acc[j] = fmaf(c1, bf2f(u1[j]), acc[j]);
            e += 2;
        }
        if (e < e1) {
            int sv = csr_src[e];
            float c0 = dinv[sv] * di;
            u16x8 u0 = hw8[(size_t)sv * 16 + f];
#pragma unroll
            for (int j = 0; j < 8; j++) acc[j] = fmaf(c0, bf2f(u0[j]), acc[j]);
        }

        const float4* b4 = (const float4*)bias;
        float4 ba = b4[f * 2], bb = b4[f * 2 + 1];
        float bv[8] = {ba.x, ba.y, ba.z, ba.w, bb.x, bb.y, bb.z, bb.w};
#pragma unroll
        for (int j = 0; j < 8; j++) {
            float r = fmaxf(acc[j] + bv[j], 0.f);   // bias + relu
            o[j] = f2bf(r);
        }
    }
    *(u16x8*)&rows[(t >> 4) * 136 + f * 8] = o;     // zeros for dead nodes
    __syncthreads();

    // mini-GEMM: D[16][NCT*16] = rows[16][128] @ WB; wave w takes tiles w, w+4,...
    int w = t >> 6, lane = t & 63;
    int cr = lane & 15;       // A row / B col within tile
    int kg = lane >> 4;       // k-group (8 elems)
    for (int ct = w; ct < NCT; ct += 4) {
        f32x4 acc4 = {0.f, 0.f, 0.f, 0.f};
#pragma unroll
        for (int ks = 0; ks < 4; ks++) {
            int kk = ks * 32 + kg * 8;
            short8v a = *(const short8v*)&rows[cr * 136 + kk];
            short8v b = *(const short8v*)(WB + (ct * 16 + cr) * 128 + kk);
            acc4 = __builtin_amdgcn_mfma_f32_16x16x32_bf16(a, b, acc4, 0, 0, 0);
        }
        // D: col = lane&15, row = (lane>>4)*4 + r
        int col = ct * 16 + cr;
#pragma unroll
        for (int r = 0; r < 4; r++) {
            int nd = blockIdx.x * 16 + kg * 4 + r;
            if (nd < n) gout[(size_t)nd * OSTRIDE + col] = f2bf(acc4[r]);
        }
    }
}

// ---------------------------------------------------------------------------
// final aggregation, 40 bf16 features (g3 padded to 64-col rows = 128 B) ->
// fp32 out. Block 320: 16 nodes, 20 lanes/node, 2 features per lane.
// ---------------------------------------------------------------------------
__global__ __launch_bounds__(320) void agg40_bf16(const u16* __restrict__ g3,
                                                  const float* __restrict__ dinv,
                                                  const int* __restrict__ row_start,
                                                  const int* __restrict__ csr_src,
                                                  const float* __restrict__ bias,
                                                  float* __restrict__ out, int n) {
    int t = threadIdx.x;
    int node = blockIdx.x * 16 + t / 20;
    int fq = t % 20;                    // features 2fq, 2fq+1
    if (node >= n) return;
    float di = dinv[node];
    float s2 = di * di;
    u16x2 v = *(const u16x2*)(g3 + (size_t)node * 64 + fq * 2);
    float a0 = bf2f(v[0]) * s2;
    float a1 = bf2f(v[1]) * s2;

    int e0 = row_start[node], e1 = row_start[node + 1];
    int e = e0;
    for (; e + 3 < e1; e += 4) {
        int s0v = csr_src[e], s1v = csr_src[e + 1], s2v = csr_src[e + 2], s3v = csr_src[e + 3];
        float c0 = dinv[s0v] * di, c1 = dinv[s1v] * di;
        float c2 = dinv[s2v] * di, c3 = dinv[s3v] * di;
        u16x2 u0 = *(const u16x2*)(g3 + (size_t)s0v * 64 + fq * 2);
        u16x2 u1 = *(const u16x2*)(g3 + (size_t)s1v * 64 + fq * 2);
        u16x2 u2 = *(const u16x2*)(g3 + (size_t)s2v * 64 + fq * 2);
        u16x2 u3 = *(const u16x2*)(g3 + (size_t)s3v * 64 + fq * 2);
        a0 = fmaf(c0, bf2f(u0[0]), a0); a1 = fmaf(c0, bf2f(u0[1]), a1);
        a0 = fmaf(c1, bf2f(u1[0]), a0); a1 = fmaf(c1, bf2f(u1[1]), a1);
        a0 = fmaf(c2, bf2f(u2[0]), a0); a1 = fmaf(c2, bf2f(u2[1]), a1);
        a0 = fmaf(c3, bf2f(u3[0]), a0); a1 = fmaf(c3, bf2f(u3[1]), a1);
    }
    if (e + 1 < e1) {
        int s0v = csr_src[e], s1v = csr_src[e + 1];
        float c0 = dinv[s0v] * di, c1 = dinv[s1v] * di;
        u16x2 u0 = *(const u16x2*)(g3 + (size_t)s0v * 64 + fq * 2);
        u16x2 u1 = *(const u16x2*)(g3 + (size_t)s1v * 64 + fq * 2);
        a0 = fmaf(c0, bf2f(u0[0]), a0); a1 = fmaf(c0, bf2f(u0[1]), a1);
        a0 = fmaf(c1, bf2f(u1[0]), a0); a1 = fmaf(c1, bf2f(u1[1]), a1);
        e += 2;
    }
    if (e < e1) {
        int sv = csr_src[e];
        float c0 = dinv[sv] * di;
        u16x2 u0 = *(const u16x2*)(g3 + (size_t)sv * 64 + fq * 2);
        a0 = fmaf(c0, bf2f(u0[0]), a0); a1 = fmaf(c0, bf2f(u0[1]), a1);
    }

    float2 b2v = *(const float2*)(bias + fq * 2);
    float2 o = make_float2(a0 + b2v.x, a1 + b2v.y);
    *(float2*)(out + (size_t)node * 40 + fq * 2) = o;
}

extern "C" void kernel_launch(void* const* d_in, const int* in_sizes, int n_in,
                              void* d_out, int out_size, void* d_ws, size_t ws_size,
                              hipStream_t stream) {
    const float* x  = (const float*)d_in[0];
    const int*   ei = (const int*)d_in[1];
    const float* W1 = (const float*)d_in[2];
    const float* b1 = (const float*)d_in[3];
    const float* W2 = (const float*)d_in[4];
    const float* b2 = (const float*)d_in[5];
    const float* W3 = (const float*)d_in[6];
    const float* b3 = (const float*)d_in[7];
    float* out = (float*)d_out;

    const int n = in_sizes[0] / 128;   // 170000
    const int E = in_sizes[1] / 2;     // 1200000
    const int nb = (n + 511) >> 9;     // 512-node buckets

    // workspace carve (256B aligned)
    char* p = (char*)d_ws;
    auto alloc = [&](size_t bytes) { void* r = (void*)p; p += (bytes + 255) & ~(size_t)255; return r; };
    int*   row_start = (int*)alloc((size_t)(n + 1) * 4);
    float* dinv      = (float*)alloc((size_t)n * 4);
    int*   csr_src   = (int*)alloc((size_t)E * 4);
    int2*  ebuf      = (int2*)alloc((size_t)E * 8);
    int*   bhist     = (int*)alloc(512 * 4);
    int*   bstart    = (int*)alloc(520 * 4);
    int*   bcur      = (int*)alloc(512 * 4);
    u16*   bufG      = (u16*)alloc((size_t)n * 128 * 2);   // gemm1 out (bf16)
    u16*   g2        = (u16*)alloc((size_t)n * 128 * 2);   // fused h1*W2 out
    u16*   g3        = (u16*)alloc((size_t)n * 64 * 2);    // fused h2*W3 out (padded)
    u16*   wt1       = (u16*)alloc(16384 * 2);
    u16*   wt2       = (u16*)alloc(16384 * 2);
    u16*   wt3       = (u16*)alloc(8192 * 2);              // [64][128], cols 40+ zero

    // --- bucketed CSR build (+ weight convert folded into histA grid) ---
    hipMemsetAsync(bhist, 0, 512 * 4, stream);
    const int ebk = (E + 4095) / 4096;
    histA_wconv<<<ebk + 160, 256, 0, stream>>>(ei, E, bhist, ebk, W1, W2, W3, wt1, wt2, wt3);
    scanA_kernel<<<1, 256, 0, stream>>>(bhist, bstart, bcur, nb);
    bucket_scatter<<<ebk, 256, 0, stream>>>(ei, E, bcur, ebuf);
    fine_fill<<<nb, 256, 0, stream>>>(ebuf, bstart, row_start, dinv, csr_src, n, nb, E);

    const int gblk = (n + 63) / 64;
    const int ablk = (n + 15) / 16;

    // --- layer 1 GEMM: bufG = bf16(x) @ W1 ---
    gemm128_mfma<<<gblk, 256, 0, stream>>>(x, wt1, bufG, n);
    // --- fused: h1 = relu(agg(bufG)+b1); g2 = h1 @ W2 ---
    agg_fuse<8, 128><<<ablk, 256, 0, stream>>>(bufG, dinv, row_start, csr_src, b1, wt2, g2, n);
    // --- fused: h2 = relu(agg(g2)+b2); g3 = h2 @ W3 (64-col padded rows) ---
    agg_fuse<3, 64><<<ablk, 256, 0, stream>>>(g2, dinv, row_start, csr_src, b2, wt3, g3, n);
    // --- final aggregation over 40 features + b3 -> logits ---
    agg40_bf16<<<ablk, 320, 0, stream>>>(g3, dinv, row_start, csr_src, b3, out, n);
}

// Round 11
// 390.789 us; speedup vs baseline: 1.0087x; 1.0087x over previous
//
#include <hip/hip_runtime.h>

typedef unsigned short u16;
typedef u16   u16x8  __attribute__((ext_vector_type(8)));
typedef u16   u16x4  __attribute__((ext_vector_type(4)));
typedef u16   u16x2  __attribute__((ext_vector_type(2)));
typedef short short8v __attribute__((ext_vector_type(8)));
typedef float f32x16  __attribute__((ext_vector_type(16)));
typedef float f32x4   __attribute__((ext_vector_type(4)));

__device__ __forceinline__ u16 f2bf(float f) {
    unsigned u = __float_as_uint(f);
    unsigned r = (u + 0x7fffu + ((u >> 16) & 1u)) >> 16;   // round-to-nearest-even
    return (u16)r;
}
__device__ __forceinline__ float bf2f(u16 h) {
    return __uint_as_float(((unsigned)h) << 16);
}

// ---------------------------------------------------------------------------
// histA (+ wconv folded into grid tail): per-bucket edge counts.
// ---------------------------------------------------------------------------
__global__ __launch_bounds__(256) void histA_wconv(const int* __restrict__ ei, int E,
                                                   int* __restrict__ bhist, int ebk,
                                                   const float* __restrict__ W1,
                                                   const float* __restrict__ W2,
                                                   const float* __restrict__ W3,
                                                   u16* __restrict__ WT1,
                                                   u16* __restrict__ WT2,
                                                   u16* __restrict__ WT3) {
    if ((int)blockIdx.x >= ebk) {
        int i = (blockIdx.x - ebk) * 256 + threadIdx.x;   // 0..40959
        if (i < 32768) {
            const float* W = (i < 16384) ? W1 : W2;
            u16* WT = (i < 16384) ? WT1 : WT2;
            int j = i & 16383;
            int k = j >> 7, col = j & 127;
            WT[col * 128 + k] = f2bf(W[j]);
        } else {
            int j = i - 32768;                    // 0..8191
            int col = j >> 7, k = j & 127;        // col 0..63
            WT3[j] = (col < 40) ? f2bf(W3[k * 40 + col]) : (u16)0;
        }
        return;
    }
    __shared__ int h[512];
    int t = threadIdx.x;
    h[t] = 0; h[t + 256] = 0;
    __syncthreads();
    int base = blockIdx.x * 4096 + t;
#pragma unroll
    for (int j = 0; j < 16; j++) {
        int e = base + j * 256;
        if (e < E) {
            int d = __builtin_nontemporal_load(ei + E + e);
            atomicAdd(&h[d >> 9], 1);
        }
    }
    __syncthreads();
    if (h[t])       atomicAdd(&bhist[t], h[t]);
    if (h[t + 256]) atomicAdd(&bhist[t + 256], h[t + 256]);
}

__global__ __launch_bounds__(256) void scanA_kernel(const int* __restrict__ bhist,
                                                    int* __restrict__ bstart,
                                                    int* __restrict__ bcur, int nb) {
    __shared__ int hh[512];
    __shared__ int ps[256];
    int t = threadIdx.x;
    hh[t]       = (t < nb) ? bhist[t] : 0;
    hh[t + 256] = (t + 256 < nb) ? bhist[t + 256] : 0;
    __syncthreads();
    int a0 = hh[2 * t], a1 = hh[2 * t + 1];
    int s = a0 + a1;
    ps[t] = s;
    __syncthreads();
    for (int off = 1; off < 256; off <<= 1) {
        int add = (t >= off) ? ps[t - off] : 0;
        __syncthreads();
        ps[t] += add;
        __syncthreads();
    }
    int ex = ps[t] - s;
    bstart[2 * t] = ex;         bcur[2 * t] = ex;
    bstart[2 * t + 1] = ex + a0; bcur[2 * t + 1] = ex + a0;
    if (t == 255) bstart[512] = ps[255];
}

__global__ __launch_bounds__(256) void bucket_scatter(const int* __restrict__ ei, int E,
                                                      int* __restrict__ bcur,
                                                      int2* __restrict__ ebuf) {
    __shared__ int h[512];
    __shared__ int gb[512];
    int t = threadIdx.x;
    h[t] = 0; h[t + 256] = 0;
    __syncthreads();
    int base = blockIdx.x * 4096 + t;
    int ss[16], dd[16], lr[16];
#pragma unroll
    for (int j = 0; j < 16; j++) {
        int e = base + j * 256;
        if (e < E) {
            ss[j] = __builtin_nontemporal_load(ei + e);
            dd[j] = __builtin_nontemporal_load(ei + E + e);
            lr[j] = atomicAdd(&h[dd[j] >> 9], 1);
        } else {
            dd[j] = -1;
        }
    }
    __syncthreads();
    if (h[t])       gb[t] = atomicAdd(&bcur[t], h[t]);
    if (h[t + 256]) gb[t + 256] = atomicAdd(&bcur[t + 256], h[t + 256]);
    __syncthreads();
#pragma unroll
    for (int j = 0; j < 16; j++) {
        if (dd[j] >= 0) {
            int b = dd[j] >> 9;
            ebuf[gb[b] + lr[j]] = make_int2(ss[j], dd[j]);
        }
    }
}

__global__ __launch_bounds__(256) void fine_fill(const int2* __restrict__ ebuf,
                                                 const int* __restrict__ bstart,
                                                 int* __restrict__ row_start,
                                                 float* __restrict__ dinv,
                                                 int* __restrict__ csr_src,
                                                 int n, int nb, int E) {
    __shared__ int h[512];
    __shared__ int cur[512];
    __shared__ int ps[256];
    int b = blockIdx.x;
    int t = threadIdx.x;
    int base = b << 9;
    int range = n - base; if (range > 512) range = 512;
    int bs = bstart[b], be = bstart[b + 1];

    h[t] = 0; h[t + 256] = 0;
    __syncthreads();
    for (int i = bs + t; i < be; i += 256) {
        int2 e = ebuf[i];
        atomicAdd(&h[e.y - base], 1);
    }
    __syncthreads();
    if (t < range)       dinv[base + t] = rsqrtf((float)(h[t] + 1));
    if (t + 256 < range) dinv[base + t + 256] = rsqrtf((float)(h[t + 256] + 1));
    int a0 = h[2 * t], a1 = h[2 * t + 1];
    int s = a0 + a1;
    ps[t] = s;
    __syncthreads();
    for (int off = 1; off < 256; off <<= 1) {
        int add = (t >= off) ? ps[t - off] : 0;
        __syncthreads();
        ps[t] += add;
        __syncthreads();
    }
    int ex = ps[t] - s;
    cur[2 * t] = ex;
    cur[2 * t + 1] = ex + a0;
    if (2 * t < range)     row_start[base + 2 * t] = bs + ex;
    if (2 * t + 1 < range) row_start[base + 2 * t + 1] = bs + ex + a0;
    if (b == nb - 1 && t == 0) row_start[n] = E;
    __syncthreads();
    for (int i = bs + t; i < be; i += 256) {
        int2 e = ebuf[i];
        int lp = atomicAdd(&cur[e.y - base], 1);
        csr_src[bs + lp] = e.x;
    }
}

// ---------------------------------------------------------------------------
// out[n x 128](bf16) = A[n x 128](fp32) @ W1[128 x 128] via bf16 MFMA.
// ---------------------------------------------------------------------------
__global__ __launch_bounds__(256) void gemm128_mfma(const float* __restrict__ A,
                                                    const u16* __restrict__ WT,
                                                    u16* __restrict__ out, int n) {
    __shared__ u16 As[64 * 128];
    __shared__ u16 Bs[128 * 128];
    const int t = threadIdx.x;
    const int r0 = blockIdx.x * 64;

#pragma unroll
    for (int j = 0; j < 8; j++) {
        int f = t + j * 256;
        int col = f >> 4;
        int k0 = (f & 15) * 8;
        u16x8 v = *(const u16x8*)(WT + col * 128 + k0);
        *(u16x8*)&Bs[col * 128 + (k0 ^ ((col & 7) << 3))] = v;
    }
#pragma unroll
    for (int j = 0; j < 8; j++) {
        int f = t + j * 256;            // 2048 float4 chunks
        int row = f >> 5;
        int k0 = (f & 31) * 4;
        float4 v = make_float4(0.f, 0.f, 0.f, 0.f);
        if (r0 + row < n) v = *(const float4*)(A + (size_t)(r0 + row) * 128 + k0);
        u16x4 b;
        b[0] = f2bf(v.x); b[1] = f2bf(v.y); b[2] = f2bf(v.z); b[3] = f2bf(v.w);
        *(u16x4*)&As[row * 128 + (k0 ^ ((row & 7) << 3))] = b;
    }
    __syncthreads();

    const int w = t >> 6, lane = t & 63;
    const int wr = (w >> 1) * 32;
    const int wc = (w & 1) * 64;
    const int lr = lane & 31;
    const int kj = (lane >> 5) * 8;
    const int swz = (lr & 7) << 3;

    f32x16 acc0, acc1;
#pragma unroll
    for (int i = 0; i < 16; i++) { acc0[i] = 0.f; acc1[i] = 0.f; }

#pragma unroll
    for (int ks = 0; ks < 8; ks++) {
        int ko = (ks * 16 + kj) ^ swz;
        short8v a  = *(const short8v*)&As[(wr + lr) * 128 + ko];
        short8v b0 = *(const short8v*)&Bs[(wc + lr) * 128 + ko];
        short8v b1 = *(const short8v*)&Bs[(wc + 32 + lr) * 128 + ko];
        acc0 = __builtin_amdgcn_mfma_f32_32x32x16_bf16(a, b0, acc0, 0, 0, 0);
        acc1 = __builtin_amdgcn_mfma_f32_32x32x16_bf16(a, b1, acc1, 0, 0, 0);
    }

    const int rb = (lane >> 5) * 4;
#pragma unroll
    for (int r = 0; r < 16; r++) {
        int rr = (r & 3) + 8 * (r >> 2) + rb;
        int row = r0 + wr + rr;
        if (row < n) {
            out[(size_t)row * 128 + wc + lr]      = f2bf(acc0[r]);
            out[(size_t)row * 128 + wc + 32 + lr] = f2bf(acc1[r]);
        }
    }
}

// ---------------------------------------------------------------------------
// Fused: pull-agg over 128 bf16 features (+bias+relu) -> 32 rows in LDS ->
// rows[32][128] @ WB[128 x NCT*16] via 16x16x32 MFMA.
// 512 thr / 32 nodes per block. Each wave owns ONE 16-col B tile, preloaded
// into registers BEFORE the gather (latency hidden) -> tail is LDS+MFMA only.
//   NCT==8: wave w -> col tile w, row tiles 0 and 1.
//   NCT<=4: wave w (w < 2*NCT) -> col tile w>>1, row tile w&1.
// ---------------------------------------------------------------------------
template <int NCT, int OSTRIDE>
__global__ __launch_bounds__(512) void agg_fuse(const u16* __restrict__ hw,
                                                const float* __restrict__ dinv,
                                                const int* __restrict__ row_start,
                                                const int* __restrict__ csr_src,
                                                const float* __restrict__ bias,
                                                const u16* __restrict__ WB,
                                                u16* __restrict__ gout, int n) {
    __shared__ u16 rows[32 * 136];
    int t = threadIdx.x;
    int w = t >> 6, lane = t & 63;
    int cr = lane & 15, kg = lane >> 4;

    // ---- preload this wave's B tile into registers (hidden under gather) ----
    const int ct = (NCT == 8) ? w : (w >> 1);
    const bool bact = (NCT == 8) ? true : (w < 2 * NCT);
    short8v bfrag[4];
    if (bact) {
#pragma unroll
        for (int ks = 0; ks < 4; ks++)
            bfrag[ks] = *(const short8v*)(WB + (ct * 16 + cr) * 128 + ks * 32 + kg * 8);
    }

    // ---- gather phase: 32 nodes, 16 lanes/node ----
    int node = blockIdx.x * 32 + (t >> 4);
    int f = t & 15;
    bool alive = node < n;
    u16x8 o = {0, 0, 0, 0, 0, 0, 0, 0};
    if (alive) {
        const u16x8* hw8 = (const u16x8*)hw;
        float di = dinv[node];
        float s2 = di * di;
        u16x8 v = hw8[(size_t)node * 16 + f];
        float acc[8];
#pragma unroll
        for (int j = 0; j < 8; j++) acc[j] = bf2f(v[j]) * s2;

        int e0 = row_start[node], e1 = row_start[node + 1];
        int e = e0;
        for (; e + 3 < e1; e += 4) {
            int s0v = csr_src[e], s1v = csr_src[e + 1], s2v = csr_src[e + 2], s3v = csr_src[e + 3];
            float c0 = dinv[s0v] * di, c1 = dinv[s1v] * di;
            float c2 = dinv[s2v] * di, c3 = dinv[s3v] * di;
            u16x8 u0 = hw8[(size_t)s0v * 16 + f];
            u16x8 u1 = hw8[(size_t)s1v * 16 + f];
            u16x8 u2 = hw8[(size_t)s2v * 16 + f];
            u16x8 u3 = hw8[(size_t)s3v * 16 + f];
#pragma unroll
            for (int j = 0; j < 8; j++) acc[j] = fmaf(c0, bf2f(u0[j]), acc[j]);
#pragma unroll
            for (int j = 0; j < 8; j++) acc[j] = fmaf(c1, bf2f(u1[j]), acc[j]);
#pragma unroll
            for (int j = 0; j < 8; j++) acc[j] = fmaf(c2, bf2f(u2[j]), acc[j]);
#pragma unroll
            for (int j = 0; j < 8; j++) acc[j] = fmaf(c3, bf2f(u3[j]), acc[j]);
        }
        if (e + 1 < e1) {
            int s0v = csr_src[e], s1v = csr_src[e + 1];
            float c0 = dinv[s0v] * di, c1 = dinv[s1v] * di;
            u16x8 u0 = hw8[(size_t)s0v * 16 + f];
            u16x8 u1 = hw8[(size_t)s1v * 16 + f];
#pragma unroll
            for (int j = 0; j < 8; j++) acc[j] = fmaf(c0, bf2f(u0[j]), acc[j]);
#pragma unroll
            for (int j = 0; j < 8; j++) acc[j] = fmaf(c1, bf2f(u1[j]), acc[j]);
            e += 2;
        }
        if (e < e1) {
            int sv = csr_src[e];
            float c0 = dinv[sv] * di;
            u16x8 u0 = hw8[(size_t)sv * 16 + f];
#pragma unroll
            for (int j = 0; j < 8; j++) acc[j] = fmaf(c0, bf2f(u0[j]), acc[j]);
        }

        const float4* b4 = (const float4*)bias;
        float4 ba = b4[f * 2], bb = b4[f * 2 + 1];
        float bv[8] = {ba.x, ba.y, ba.z, ba.w, bb.x, bb.y, bb.z, bb.w};
#pragma unroll
        for (int j = 0; j < 8; j++) {
            float r = fmaxf(acc[j] + bv[j], 0.f);   // bias + relu
            o[j] = f2bf(r);
        }
    }
    *(u16x8*)&rows[(t >> 4) * 136 + f * 8] = o;     // zeros for dead nodes
    __syncthreads();

    // ---- mini-GEMM tail: registers (B) x LDS (A), no VMEM ----
    if (bact) {
        int col = ct * 16 + cr;
#pragma unroll
        for (int i = 0; i < (NCT == 8 ? 2 : 1); i++) {
            int rt = (NCT == 8) ? i : (w & 1);
            f32x4 acc4 = {0.f, 0.f, 0.f, 0.f};
#pragma unroll
            for (int ks = 0; ks < 4; ks++) {
                short8v a = *(const short8v*)&rows[(rt * 16 + cr) * 136 + ks * 32 + kg * 8];
                acc4 = __builtin_amdgcn_mfma_f32_16x16x32_bf16(a, bfrag[ks], acc4, 0, 0, 0);
            }
            // D: col = lane&15, row = (lane>>4)*4 + r
#pragma unroll
            for (int r = 0; r < 4; r++) {
                int nd = blockIdx.x * 32 + rt * 16 + kg * 4 + r;
                if (nd < n) gout[(size_t)nd * OSTRIDE + col] = f2bf(acc4[r]);
            }
        }
    }
}

// ---------------------------------------------------------------------------
// final aggregation, 40 bf16 features (g3 padded to 64-col rows = 128 B) ->
// fp32 out. Block 320: 16 nodes, 20 lanes/node, 2 features per lane.
// ---------------------------------------------------------------------------
__global__ __launch_bounds__(320) void agg40_bf16(const u16* __restrict__ g3,
                                                  const float* __restrict__ dinv,
                                                  const int* __restrict__ row_start,
                                                  const int* __restrict__ csr_src,
                                                  const float* __restrict__ bias,
                                                  float* __restrict__ out, int n) {
    int t = threadIdx.x;
    int node = blockIdx.x * 16 + t / 20;
    int fq = t % 20;                    // features 2fq, 2fq+1
    if (node >= n) return;
    float di = dinv[node];
    float s2 = di * di;
    u16x2 v = *(const u16x2*)(g3 + (size_t)node * 64 + fq * 2);
    float a0 = bf2f(v[0]) * s2;
    float a1 = bf2f(v[1]) * s2;

    int e0 = row_start[node], e1 = row_start[node + 1];
    int e = e0;
    for (; e + 3 < e1; e += 4) {
        int s0v = csr_src[e], s1v = csr_src[e + 1], s2v = csr_src[e + 2], s3v = csr_src[e + 3];
        float c0 = dinv[s0v] * di, c1 = dinv[s1v] * di;
        float c2 = dinv[s2v] * di, c3 = dinv[s3v] * di;
        u16x2 u0 = *(const u16x2*)(g3 + (size_t)s0v * 64 + fq * 2);
        u16x2 u1 = *(const u16x2*)(g3 + (size_t)s1v * 64 + fq * 2);
        u16x2 u2 = *(const u16x2*)(g3 + (size_t)s2v * 64 + fq * 2);
        u16x2 u3 = *(const u16x2*)(g3 + (size_t)s3v * 64 + fq * 2);
        a0 = fmaf(c0, bf2f(u0[0]), a0); a1 = fmaf(c0, bf2f(u0[1]), a1);
        a0 = fmaf(c1, bf2f(u1[0]), a0); a1 = fmaf(c1, bf2f(u1[1]), a1);
        a0 = fmaf(c2, bf2f(u2[0]), a0); a1 = fmaf(c2, bf2f(u2[1]), a1);
        a0 = fmaf(c3, bf2f(u3[0]), a0); a1 = fmaf(c3, bf2f(u3[1]), a1);
    }
    if (e + 1 < e1) {
        int s0v = csr_src[e], s1v = csr_src[e + 1];
        float c0 = dinv[s0v] * di, c1 = dinv[s1v] * di;
        u16x2 u0 = *(const u16x2*)(g3 + (size_t)s0v * 64 + fq * 2);
        u16x2 u1 = *(const u16x2*)(g3 + (size_t)s1v * 64 + fq * 2);
        a0 = fmaf(c0, bf2f(u0[0]), a0); a1 = fmaf(c0, bf2f(u0[1]), a1);
        a0 = fmaf(c1, bf2f(u1[0]), a0); a1 = fmaf(c1, bf2f(u1[1]), a1);
        e += 2;
    }
    if (e < e1) {
        int sv = csr_src[e];
        float c0 = dinv[sv] * di;
        u16x2 u0 = *(const u16x2*)(g3 + (size_t)sv * 64 + fq * 2);
        a0 = fmaf(c0, bf2f(u0[0]), a0); a1 = fmaf(c0, bf2f(u0[1]), a1);
    }

    float2 b2v = *(const float2*)(bias + fq * 2);
    float2 o = make_float2(a0 + b2v.x, a1 + b2v.y);
    *(float2*)(out + (size_t)node * 40 + fq * 2) = o;
}

extern "C" void kernel_launch(void* const* d_in, const int* in_sizes, int n_in,
                              void* d_out, int out_size, void* d_ws, size_t ws_size,
                              hipStream_t stream) {
    const float* x  = (const float*)d_in[0];
    const int*   ei = (const int*)d_in[1];
    const float* W1 = (const float*)d_in[2];
    const float* b1 = (const float*)d_in[3];
    const float* W2 = (const float*)d_in[4];
    const float* b2 = (const float*)d_in[5];
    const float* W3 = (const float*)d_in[6];
    const float* b3 = (const float*)d_in[7];
    float* out = (float*)d_out;

    const int n = in_sizes[0] / 128;   // 170000
    const int E = in_sizes[1] / 2;     // 1200000
    const int nb = (n + 511) >> 9;     // 512-node buckets

    // workspace carve (256B aligned)
    char* p = (char*)d_ws;
    auto alloc = [&](size_t bytes) { void* r = (void*)p; p += (bytes + 255) & ~(size_t)255; return r; };
    int*   row_start = (int*)alloc((size_t)(n + 1) * 4);
    float* dinv      = (float*)alloc((size_t)n * 4);
    int*   csr_src   = (int*)alloc((size_t)E * 4);
    int2*  ebuf      = (int2*)alloc((size_t)E * 8);
    int*   bhist     = (int*)alloc(512 * 4);
    int*   bstart    = (int*)alloc(520 * 4);
    int*   bcur      = (int*)alloc(512 * 4);
    u16*   bufG      = (u16*)alloc((size_t)n * 128 * 2);   // gemm1 out (bf16)
    u16*   g2        = (u16*)alloc((size_t)n * 128 * 2);   // fused h1*W2 out
    u16*   g3        = (u16*)alloc((size_t)n * 64 * 2);    // fused h2*W3 out (padded)
    u16*   wt1       = (u16*)alloc(16384 * 2);
    u16*   wt2       = (u16*)alloc(16384 * 2);
    u16*   wt3       = (u16*)alloc(8192 * 2);              // [64][128], cols 40+ zero

    // --- bucketed CSR build (+ weight convert folded into histA grid) ---
    hipMemsetAsync(bhist, 0, 512 * 4, stream);
    const int ebk = (E + 4095) / 4096;
    histA_wconv<<<ebk + 160, 256, 0, stream>>>(ei, E, bhist, ebk, W1, W2, W3, wt1, wt2, wt3);
    scanA_kernel<<<1, 256, 0, stream>>>(bhist, bstart, bcur, nb);
    bucket_scatter<<<ebk, 256, 0, stream>>>(ei, E, bcur, ebuf);
    fine_fill<<<nb, 256, 0, stream>>>(ebuf, bstart, row_start, dinv, csr_src, n, nb, E);

    const int gblk = (n + 63) / 64;
    const int afblk = (n + 31) / 32;
    const int ablk = (n + 15) / 16;

    // --- layer 1 GEMM: bufG = bf16(x) @ W1 ---
    gemm128_mfma<<<gblk, 256, 0, stream>>>(x, wt1, bufG, n);
    // --- fused: h1 = relu(agg(bufG)+b1); g2 = h1 @ W2 (B preloaded to regs) ---
    agg_fuse<8, 128><<<afblk, 512, 0, stream>>>(bufG, dinv, row_start, csr_src, b1, wt2, g2, n);
    // --- fused: h2 = relu(agg(g2)+b2); g3 = h2 @ W3 (64-col padded rows) ---
    agg_fuse<3, 64><<<afblk, 512, 0, stream>>>(g2, dinv, row_start, csr_src, b2, wt3, g3, n);
    // --- final aggregation over 40 features + b3 -> logits ---
    agg40_bf16<<<ablk, 320, 0, stream>>>(g3, dinv, row_start, csr_src, b3, out, n);
}